// Round 4
// baseline (690.178 us; speedup 1.0000x reference)
//
#include <hip/hip_runtime.h>

#define NN 100000
#define NE 1000000
#define DIM 64
#define TN 32           // nodes per transform tile (NN % TN == 0)
#define KDIM 192        // concat inner dim: [agg0 | agg1 | relu(x)]
#define SCHUNK 1024     // elements per scan block
#define SBLOCKS ((NN + SCHUNK - 1) / SCHUNK)   // 98

// ---------------- CSR build (once per call, reused by all 3 layers) ----------
__global__ __launch_bounds__(256) void zero_counts(int* cnt) {
    int i = blockIdx.x * 256 + threadIdx.x;
    if (i < NN) cnt[i] = 0;
}

__global__ __launch_bounds__(256) void count_dst(const int* __restrict__ dst,
                                                 int* __restrict__ cnt) {
    int e = blockIdx.x * 256 + threadIdx.x;
    if (e < NE) atomicAdd(&cnt[dst[e]], 1);
}

__global__ __launch_bounds__(256) void scan_partial(const int* __restrict__ cnt,
                                                    int* __restrict__ bsum) {
    int t = threadIdx.x, lane = t & 63, wid = t >> 6;
    int base = blockIdx.x * SCHUNK + t * 4;
    int s = 0;
#pragma unroll
    for (int k = 0; k < 4; ++k) {
        int i = base + k;
        if (i < NN) s += cnt[i];
    }
#pragma unroll
    for (int off = 32; off > 0; off >>= 1) s += __shfl_down(s, off, 64);
    __shared__ int wtot[4];
    if (lane == 0) wtot[wid] = s;
    __syncthreads();
    if (t == 0) bsum[blockIdx.x] = wtot[0] + wtot[1] + wtot[2] + wtot[3];
}

__global__ __launch_bounds__(128) void scan_bsums(const int* __restrict__ bsum,
                                                  int* __restrict__ bsum_ex) {
    __shared__ int sh[128];
    int t = threadIdx.x;
    int v = (t < SBLOCKS) ? bsum[t] : 0;
    sh[t] = v;
    __syncthreads();
    for (int off = 1; off < 128; off <<= 1) {
        int u = (t >= off) ? sh[t - off] : 0;
        __syncthreads();
        sh[t] += u;
        __syncthreads();
    }
    if (t < SBLOCKS) bsum_ex[t] = sh[t] - v;   // exclusive
}

__global__ __launch_bounds__(256) void scan_final(const int* __restrict__ cnt,
                                                  const int* __restrict__ bsum_ex,
                                                  int* __restrict__ row_ptr,
                                                  int* __restrict__ cursor) {
    int t = threadIdx.x, lane = t & 63, wid = t >> 6;
    int base = blockIdx.x * SCHUNK + t * 4;
    int c[4];
#pragma unroll
    for (int k = 0; k < 4; ++k) {
        int i = base + k;
        c[k] = (i < NN) ? cnt[i] : 0;
    }
    int s = c[0] + c[1] + c[2] + c[3];
    int incl = s;
#pragma unroll
    for (int off = 1; off < 64; off <<= 1) {
        int u = __shfl_up(incl, off, 64);
        if (lane >= off) incl += u;
    }
    __shared__ int wtot[4];
    if (lane == 63) wtot[wid] = incl;
    __syncthreads();
    int woff = 0;
    for (int w = 0; w < wid; ++w) woff += wtot[w];
    int run = bsum_ex[blockIdx.x] + woff + (incl - s);
#pragma unroll
    for (int k = 0; k < 4; ++k) {
        int i = base + k;
        if (i < NN) { row_ptr[i] = run; cursor[i] = run; }
        run += c[k];
    }
}

__global__ __launch_bounds__(256) void fill_edges(const int* __restrict__ src,
                                                  const int* __restrict__ dst,
                                                  const int* __restrict__ et,
                                                  int* __restrict__ cursor,
                                                  int* __restrict__ epack) {
    int e = blockIdx.x * 256 + threadIdx.x;
    if (e < NE) {
        int pos = atomicAdd(&cursor[dst[e]], 1);
        epack[pos] = src[e] * 2 + et[e];  // x row = pack>>1, relation = pack&1
    }
}

// ---------------- Per-relation aggregation of raw x (gather, no atomics) ----
// out_i = W0 (sum_{et=0} act(x_j)) + W1 (sum_{et=1} act(x_j)) + act(x_i)Ws + b
// This kernel computes agg[n][0][:] and agg[n][1][:] = per-relation sums of
// act(x_src). One wave per node; 64 contiguous dims = 64 lanes.
__global__ __launch_bounds__(256) void rgcn_aggregate_x(
    const float* __restrict__ x, const int* __restrict__ row_ptr,
    const int* __restrict__ cnt, const int* __restrict__ epack,
    float* __restrict__ agg, int relu_in)
{
    int t = threadIdx.x, lane = t & 63, wid = t >> 6;
    int n = blockIdx.x * 4 + wid;
    if (n >= NN) return;
    int start = row_ptr[n], deg = cnt[n];
    float acc0 = 0.f, acc1 = 0.f;
    for (int base = 0; base < deg; base += 64) {
        int rem = deg - base; if (rem > 64) rem = 64;
        int ev = (lane < rem) ? epack[start + base + lane] : 0;
#pragma unroll 4
        for (int j = 0; j < rem; ++j) {
            int p = __shfl(ev, j, 64);          // wave-uniform
            float v = x[(size_t)(p >> 1) * DIM + lane];
            if (relu_in) v = fmaxf(v, 0.f);
            if (p & 1) acc1 += v; else acc0 += v;   // uniform branch, no divergence
        }
    }
    agg[(size_t)n * 128 + lane]      = acc0;
    agg[(size_t)n * 128 + 64 + lane] = acc1;
}

// ---------------- Transform: out = [agg0|agg1|act(x)] @ [W0;W1;Ws] + b ------
// Single 192x64 GEMM per node. Block = 256 thr = 4 waves; 32-node tile staged
// in LDS; each wave computes 8 nodes (one W LDS read feeds 8 FMAs; Z reads are
// wave-uniform b128 broadcasts). Lane j owns output dim j.
// NN % TN == 0 -> no tail guards.
// x/out may alias (in-place layer): each block reads exactly the x rows it
// writes, fully staged into LDS before the write. Do NOT __restrict__ x/out.
__global__ __launch_bounds__(256) void rgcn_transform2(
    const float* x, const float* __restrict__ agg,
    const float* __restrict__ W, const float* __restrict__ Ws,
    const float* __restrict__ bias, float* out, int relu_in)
{
    __shared__ float sW[KDIM * DIM];   // 48 KB: rows 0..127 = W[2][64][64], 128..191 = Ws
    __shared__ float sZ[TN * KDIM];    // 24 KB

    int t = threadIdx.x, lane = t & 63, wid = t >> 6;

    {
        const float4* Wv  = (const float4*)W;    // 2048 float4
        const float4* Wsv = (const float4*)Ws;   // 1024 float4
        float4* sWv = (float4*)sW;
        for (int i = t; i < 2048; i += 256) sWv[i] = Wv[i];
        for (int i = t; i < 1024; i += 256) sWv[2048 + i] = Wsv[i];
    }
    float bv = bias[lane];

    int n0 = blockIdx.x * TN;
    {
        // agg part: 32 nodes x 128 floats = 1024 float4
        const float4* av = (const float4*)(agg + (size_t)n0 * 128);
        for (int i = t; i < 1024; i += 256) {
            int node = i >> 5, c = i & 31;       // 32 float4 per node
            *(float4*)&sZ[node * KDIM + c * 4] = av[i];
        }
        // x part: 32 nodes x 64 floats = 512 float4, relu applied on read
        const float4* xv = (const float4*)(x + (size_t)n0 * DIM);
        for (int i = t; i < 512; i += 256) {
            int node = i >> 4, c = i & 15;       // 16 float4 per node
            float4 v = xv[i];
            if (relu_in) {
                v.x = fmaxf(v.x, 0.f); v.y = fmaxf(v.y, 0.f);
                v.z = fmaxf(v.z, 0.f); v.w = fmaxf(v.w, 0.f);
            }
            *(float4*)&sZ[node * KDIM + 128 + c * 4] = v;
        }
    }
    __syncthreads();

    float acc[8];
#pragma unroll
    for (int k = 0; k < 8; ++k) acc[k] = bv;

    int zb = wid * 8 * KDIM;
#pragma unroll 4
    for (int d4 = 0; d4 < KDIM / 4; ++d4) {
        float w0 = sW[(d4 * 4 + 0) * DIM + lane];
        float w1 = sW[(d4 * 4 + 1) * DIM + lane];
        float w2 = sW[(d4 * 4 + 2) * DIM + lane];
        float w3 = sW[(d4 * 4 + 3) * DIM + lane];
#pragma unroll
        for (int k = 0; k < 8; ++k) {
            float4 z = *(const float4*)&sZ[zb + k * KDIM + d4 * 4];  // broadcast
            acc[k] = fmaf(z.x, w0, acc[k]);
            acc[k] = fmaf(z.y, w1, acc[k]);
            acc[k] = fmaf(z.z, w2, acc[k]);
            acc[k] = fmaf(z.w, w3, acc[k]);
        }
    }
#pragma unroll
    for (int k = 0; k < 8; ++k) {
        int n = n0 + wid * 8 + k;
        out[(size_t)n * DIM + lane] = acc[k];
    }
}

extern "C" void kernel_launch(void* const* d_in, const int* in_sizes, int n_in,
                              void* d_out, int out_size, void* d_ws, size_t ws_size,
                              hipStream_t stream)
{
    const float* feat = (const float*)d_in[0];
    const int*   src  = (const int*)d_in[1];
    const int*   dst  = (const int*)d_in[2];
    const int*   et   = (const int*)d_in[3];
    const float* W[3]  = { (const float*)d_in[4], (const float*)d_in[7], (const float*)d_in[10] };
    const float* Ws[3] = { (const float*)d_in[5], (const float*)d_in[8], (const float*)d_in[11] };
    const float* b[3]  = { (const float*)d_in[6], (const float*)d_in[9], (const float*)d_in[12] };

    // Workspace (~82 MB):
    //   agg  [NN][2][DIM] fp32  51.2 MB
    //   bufA [NN][DIM]    fp32  25.6 MB
    //   epack [NE] int  4.0 MB; cnt/row_ptr/cursor [NN] int; bsum/bsum_ex
    float* agg  = (float*)d_ws;
    float* bufA = agg + (size_t)NN * 2 * DIM;
    int* epack   = (int*)(bufA + (size_t)NN * DIM);
    int* cnt     = epack + NE;
    int* row_ptr = cnt + NN;
    int* cursor  = row_ptr + NN;
    int* bsum    = cursor + NN;
    int* bsum_ex = bsum + SBLOCKS;
    float* outF  = (float*)d_out;

    const dim3 tb(256);
    const int ngrid = (NN + 255) / 256;   // 391
    const int egrid = (NE + 255) / 256;   // 3907
    const int tgrid = NN / TN;            // 3125 (exact)
    const int agrid = NN / 4;             // 25000 (exact)

    // Build CSR (same indices for all 3 layers)
    zero_counts<<<ngrid, tb, 0, stream>>>(cnt);
    count_dst<<<egrid, tb, 0, stream>>>(dst, cnt);
    scan_partial<<<SBLOCKS, tb, 0, stream>>>(cnt, bsum);
    scan_bsums<<<1, 128, 0, stream>>>(bsum, bsum_ex);
    scan_final<<<SBLOCKS, tb, 0, stream>>>(cnt, bsum_ex, row_ptr, cursor);
    fill_edges<<<egrid, tb, 0, stream>>>(src, dst, et, cursor, epack);

    // Layer 0 (raw features, no relu)
    rgcn_aggregate_x<<<agrid, tb, 0, stream>>>(feat, row_ptr, cnt, epack, agg, 0);
    rgcn_transform2<<<tgrid, tb, 0, stream>>>(feat, agg, W[0], Ws[0], b[0], bufA, 0);
    // Layer 1 (relu on reads of bufA; in-place)
    rgcn_aggregate_x<<<agrid, tb, 0, stream>>>(bufA, row_ptr, cnt, epack, agg, 1);
    rgcn_transform2<<<tgrid, tb, 0, stream>>>(bufA, agg, W[1], Ws[1], b[1], bufA, 1);
    // Layer 2 (relu on reads; final output pre-activation -> d_out)
    rgcn_aggregate_x<<<agrid, tb, 0, stream>>>(bufA, row_ptr, cnt, epack, agg, 1);
    rgcn_transform2<<<tgrid, tb, 0, stream>>>(bufA, agg, W[2], Ws[2], b[2], outF, 1);
}

// Round 5
// 452.694 us; speedup vs baseline: 1.5246x; 1.5246x over previous
//
#include <hip/hip_runtime.h>

#define NN 100000
#define NE 1000000
#define DIM 64
#define KDIM 192        // concat inner dim: [agg0 | agg1 | x]
#define ZPITCH 200      // LDS row pitch in bf16 (192 + 8 pad -> 400 B, 2-way banks)
#define SCHUNK 1024
#define SBLOCKS ((NN + SCHUNK - 1) / SCHUNK)   // 98

typedef __attribute__((ext_vector_type(8))) short short8;
typedef __attribute__((ext_vector_type(4))) float f32x4;

__device__ __forceinline__ float bf2f(ushort u) {
    union { uint i; float f; } c; c.i = ((uint)u) << 16; return c.f;
}
__device__ __forceinline__ ushort f2bf(float f) {
    union { float f; uint i; } c; c.f = f;
    uint u = c.i;
    return (ushort)((u + 0x7FFFu + ((u >> 16) & 1u)) >> 16);   // RNE
}

// ---------------- CSR build ----------------
__global__ __launch_bounds__(256) void zero_counts(int* cnt) {
    int i = blockIdx.x * 256 + threadIdx.x;
    if (i < NN) cnt[i] = 0;
}

// Count in-degree AND record each edge's rank within its dst (atomic return).
__global__ __launch_bounds__(256) void count_rank(const int* __restrict__ dst,
                                                  int* __restrict__ cnt,
                                                  int* __restrict__ rank) {
    int e = blockIdx.x * 256 + threadIdx.x;
    if (e < NE) rank[e] = atomicAdd(&cnt[dst[e]], 1);
}

__global__ __launch_bounds__(256) void scan_partial(const int* __restrict__ cnt,
                                                    int* __restrict__ bsum) {
    int t = threadIdx.x, lane = t & 63, wid = t >> 6;
    int base = blockIdx.x * SCHUNK + t * 4;
    int s = 0;
#pragma unroll
    for (int k = 0; k < 4; ++k) {
        int i = base + k;
        if (i < NN) s += cnt[i];
    }
#pragma unroll
    for (int off = 32; off > 0; off >>= 1) s += __shfl_down(s, off, 64);
    __shared__ int wtot[4];
    if (lane == 0) wtot[wid] = s;
    __syncthreads();
    if (t == 0) bsum[blockIdx.x] = wtot[0] + wtot[1] + wtot[2] + wtot[3];
}

__global__ __launch_bounds__(128) void scan_bsums(const int* __restrict__ bsum,
                                                  int* __restrict__ bsum_ex) {
    __shared__ int sh[128];
    int t = threadIdx.x;
    int v = (t < SBLOCKS) ? bsum[t] : 0;
    sh[t] = v;
    __syncthreads();
    for (int off = 1; off < 128; off <<= 1) {
        int u = (t >= off) ? sh[t - off] : 0;
        __syncthreads();
        sh[t] += u;
        __syncthreads();
    }
    if (t < SBLOCKS) bsum_ex[t] = sh[t] - v;
}

__global__ __launch_bounds__(256) void scan_final(const int* __restrict__ cnt,
                                                  const int* __restrict__ bsum_ex,
                                                  int* __restrict__ row_ptr) {
    int t = threadIdx.x, lane = t & 63, wid = t >> 6;
    int base = blockIdx.x * SCHUNK + t * 4;
    int c[4];
#pragma unroll
    for (int k = 0; k < 4; ++k) {
        int i = base + k;
        c[k] = (i < NN) ? cnt[i] : 0;
    }
    int s = c[0] + c[1] + c[2] + c[3];
    int incl = s;
#pragma unroll
    for (int off = 1; off < 64; off <<= 1) {
        int u = __shfl_up(incl, off, 64);
        if (lane >= off) incl += u;
    }
    __shared__ int wtot[4];
    if (lane == 63) wtot[wid] = incl;
    __syncthreads();
    int woff = 0;
    for (int w = 0; w < wid; ++w) woff += wtot[w];
    int run = bsum_ex[blockIdx.x] + woff + (incl - s);
#pragma unroll
    for (int k = 0; k < 4; ++k) {
        int i = base + k;
        if (i < NN) row_ptr[i] = run;
        run += c[k];
    }
}

// Fill: pos known without atomics (rank from count pass).
__global__ __launch_bounds__(256) void fill_edges2(const int* __restrict__ src,
                                                   const int* __restrict__ dst,
                                                   const int* __restrict__ et,
                                                   const int* __restrict__ rank,
                                                   const int* __restrict__ row_ptr,
                                                   int* __restrict__ epack) {
    int e = blockIdx.x * 256 + threadIdx.x;
    if (e < NE) {
        int pos = row_ptr[dst[e]] + rank[e];
        epack[pos] = src[e] * 2 + et[e];   // row = pack>>1, relation = pack&1
    }
}

// ---------------- Feature convert (fp32 -> bf16 table, no relu) -------------
__global__ __launch_bounds__(256) void convert_feat(const float* __restrict__ x,
                                                    ushort* __restrict__ xb) {
    int i = blockIdx.x * 256 + threadIdx.x;   // over NN*16 float4s (exact)
    float4 v = ((const float4*)x)[i];
    union { ushort u[4]; uint2 w; } o;
    o.u[0] = f2bf(v.x); o.u[1] = f2bf(v.y); o.u[2] = f2bf(v.z); o.u[3] = f2bf(v.w);
    *(uint2*)(xb + (size_t)i * 4) = o.w;
}

// ---------------- Weight prep: Wcat (192x64) -> WT hi/lo [2][64][192] bf16 --
// Wcat[k][n]: k<128 -> W[k*64+n] (W is [2][64][64] contiguous), else Ws[(k-128)*64+n].
// wt[n*192+k] = bf16_hi, wt[12288 + n*192+k] = bf16_lo  (hi+lo ~ fp32 weight)
__global__ __launch_bounds__(256) void prep_w(const float* __restrict__ W,
                                              const float* __restrict__ Ws,
                                              ushort* __restrict__ wt) {
    int idx = blockIdx.x * 256 + threadIdx.x;  // 0..12287 (grid 48)
    int k = idx >> 6, n = idx & 63;
    float v = (k < 128) ? W[k * 64 + n] : Ws[(k - 128) * 64 + n];
    ushort h = f2bf(v);
    ushort l = f2bf(v - bf2f(h));
    wt[n * 192 + k] = h;
    wt[12288 + n * 192 + k] = l;
}

// ---------------- Aggregation (bf16 gathers, fp32 accum, bf16 agg out) ------
// agg[n][0:64] = sum_{et=0} xb[src]; agg[n][64:128] = sum_{et=1} xb[src].
// One wave per node; lane = feature dim; 128 B coalesced gather per edge.
__global__ __launch_bounds__(256) void rgcn_aggregate_b(
    const ushort* __restrict__ xb, const int* __restrict__ row_ptr,
    const int* __restrict__ cnt, const int* __restrict__ epack,
    ushort* __restrict__ agg)
{
    int t = threadIdx.x, lane = t & 63, wid = t >> 6;
    int n = blockIdx.x * 4 + wid;
    if (n >= NN) return;
    int start = row_ptr[n], deg = cnt[n];
    float acc0 = 0.f, acc1 = 0.f;
    for (int base = 0; base < deg; base += 64) {
        int rem = deg - base; if (rem > 64) rem = 64;
        int ev = (lane < rem) ? epack[start + base + lane] : 0;
#pragma unroll 4
        for (int j = 0; j < rem; ++j) {
            int p = __shfl(ev, j, 64);                    // wave-uniform
            float v = bf2f(xb[(size_t)(p >> 1) * DIM + lane]);
            if (p & 1) acc1 += v; else acc0 += v;         // uniform branch
        }
    }
    agg[(size_t)n * 128 + lane]      = f2bf(acc0);
    agg[(size_t)n * 128 + 64 + lane] = f2bf(acc1);
}

// ---------------- MFMA transform ----------------
// out[n][:] = [agg0|agg1|xb] (bf16) @ (Wh+Wl) + b   via mfma_f32_16x16x32_bf16.
// Block = 256 thr = 4 waves, 64-node tile in LDS (Zh only, 25.6 KB).
// Wave w owns output tile n0 = w*16; its 12 b-frags (6 K-steps x hi/lo) live in
// VGPRs for the whole block (zero LDS traffic for W). Per K-step: 4 a-frag
// ds_read_b128 + 8 MFMA -> MFMA-bound.
// A-frag: A[m=lane&15][k=quad*8+j] ; C/D: col=lane&15, row=quad*4+reg (guide §3).
// mode=0: write xbn = bf16(relu(out)) ; mode=1: write fp32 out (final layer).
__global__ __launch_bounds__(256) void rgcn_transform_mfma(
    const ushort* __restrict__ agg,   // [NN][128] bf16
    const ushort* __restrict__ xb,    // [NN][64]  bf16
    const ushort* __restrict__ wt,    // [2][64][192] bf16 (hi, lo)
    const float* __restrict__ bias,
    float* __restrict__ outf,
    ushort* __restrict__ xbn,
    int mode)
{
    __shared__ ushort sZ[64 * ZPITCH];   // 25.6 KB

    int t = threadIdx.x, lane = t & 63, wid = t >> 6;
    int quad = lane >> 4, l16 = lane & 15;

    // Preload this wave's B fragments: B[k][n], n = wid*16 + l16, k = kk*32+quad*8+j
    short8 bh[6], bl[6];
    {
        const ushort* wh = wt + (size_t)(wid * 16 + l16) * 192;
        const ushort* wl = wh + 64 * 192;
#pragma unroll
        for (int kk = 0; kk < 6; ++kk) {
            bh[kk] = *(const short8*)(wh + kk * 32 + quad * 8);
            bl[kk] = *(const short8*)(wl + kk * 32 + quad * 8);
        }
    }
    float bv = bias[wid * 16 + l16];

    int n0 = blockIdx.x * 64;
    // Stage Z tile: agg part (cols 0..127) then xb part (cols 128..191), bf16.
    for (int i = t; i < 1024; i += 256) {           // 64 rows x 16 uint4
        int node = i >> 4, c8 = i & 15;
        int n = n0 + node;
        uint4 v = {0u, 0u, 0u, 0u};
        if (n < NN) v = *(const uint4*)(agg + (size_t)n * 128 + c8 * 8);
        *(uint4*)(sZ + node * ZPITCH + c8 * 8) = v;
    }
    for (int i = t; i < 512; i += 256) {            // 64 rows x 8 uint4
        int node = i >> 3, c8 = i & 7;
        int n = n0 + node;
        uint4 v = {0u, 0u, 0u, 0u};
        if (n < NN) v = *(const uint4*)(xb + (size_t)n * DIM + c8 * 8);
        *(uint4*)(sZ + node * ZPITCH + 128 + c8 * 8) = v;
    }
    __syncthreads();

    f32x4 acc[4];
#pragma unroll
    for (int mt = 0; mt < 4; ++mt) acc[mt] = (f32x4){bv, bv, bv, bv};  // bias via C

#pragma unroll
    for (int kk = 0; kk < 6; ++kk) {
#pragma unroll
        for (int mt = 0; mt < 4; ++mt) {
            short8 a = *(const short8*)(sZ + (mt * 16 + l16) * ZPITCH + kk * 32 + quad * 8);
            acc[mt] = __builtin_amdgcn_mfma_f32_16x16x32_bf16(a, bh[kk], acc[mt], 0, 0, 0);
            acc[mt] = __builtin_amdgcn_mfma_f32_16x16x32_bf16(a, bl[kk], acc[mt], 0, 0, 0);
        }
    }

    int col = wid * 16 + l16;
#pragma unroll
    for (int mt = 0; mt < 4; ++mt) {
#pragma unroll
        for (int r = 0; r < 4; ++r) {
            int node = n0 + mt * 16 + quad * 4 + r;
            if (node < NN) {
                float v = acc[mt][r];
                if (mode) outf[(size_t)node * DIM + col] = v;
                else      xbn[(size_t)node * DIM + col] = f2bf(fmaxf(v, 0.f));
            }
        }
    }
}

extern "C" void kernel_launch(void* const* d_in, const int* in_sizes, int n_in,
                              void* d_out, int out_size, void* d_ws, size_t ws_size,
                              hipStream_t stream)
{
    const float* feat = (const float*)d_in[0];
    const int*   src  = (const int*)d_in[1];
    const int*   dst  = (const int*)d_in[2];
    const int*   et   = (const int*)d_in[3];
    const float* W[3]  = { (const float*)d_in[4], (const float*)d_in[7], (const float*)d_in[10] };
    const float* Ws[3] = { (const float*)d_in[5], (const float*)d_in[8], (const float*)d_in[11] };
    const float* b[3]  = { (const float*)d_in[6], (const float*)d_in[9], (const float*)d_in[12] };

    // Workspace (~60 MB):
    //   agg   ushort[NN*128]  25.6 MB
    //   xbuf0 ushort[NN*64]   12.8 MB
    //   xbuf1 ushort[NN*64]   12.8 MB
    //   wt    ushort[3][2*12288]  147 KB
    //   epack/rank int[NE] 2x4 MB; cnt/row_ptr int[NN]; bsum/bsum_ex
    ushort* agg   = (ushort*)d_ws;
    ushort* xbuf0 = agg + (size_t)NN * 128;
    ushort* xbuf1 = xbuf0 + (size_t)NN * 64;
    ushort* wt    = xbuf1 + (size_t)NN * 64;
    int* epack   = (int*)(wt + 3 * 2 * 12288);
    int* rank    = epack + NE;
    int* cnt     = rank + NE;
    int* row_ptr = cnt + NN;
    int* bsum    = row_ptr + NN;
    int* bsum_ex = bsum + SBLOCKS;
    float* outF  = (float*)d_out;

    const dim3 tb(256);
    const int ngrid = (NN + 255) / 256;   // 391
    const int egrid = (NE + 255) / 256;   // 3907
    const int tgrid = (NN + 63) / 64;     // 1563
    const int agrid = NN / 4;             // 25000

    // CSR build
    zero_counts<<<ngrid, tb, 0, stream>>>(cnt);
    count_rank<<<egrid, tb, 0, stream>>>(dst, cnt, rank);
    scan_partial<<<SBLOCKS, tb, 0, stream>>>(cnt, bsum);
    scan_bsums<<<1, 128, 0, stream>>>(bsum, bsum_ex);
    scan_final<<<SBLOCKS, tb, 0, stream>>>(cnt, bsum_ex, row_ptr);
    fill_edges2<<<egrid, tb, 0, stream>>>(src, dst, et, rank, row_ptr, epack);

    // Per-layer weight prep + feature table
    prep_w<<<48, tb, 0, stream>>>(W[0], Ws[0], wt);
    prep_w<<<48, tb, 0, stream>>>(W[1], Ws[1], wt + 2 * 12288);
    prep_w<<<48, tb, 0, stream>>>(W[2], Ws[2], wt + 4 * 12288);
    convert_feat<<<NN * 16 / 256, tb, 0, stream>>>(feat, xbuf0);

    // Layer 0: xbuf0 (raw feats) -> xbuf1 = bf16(relu(out0))
    rgcn_aggregate_b<<<agrid, tb, 0, stream>>>(xbuf0, row_ptr, cnt, epack, agg);
    rgcn_transform_mfma<<<tgrid, tb, 0, stream>>>(agg, xbuf0, wt, b[0], nullptr, xbuf1, 0);
    // Layer 1: xbuf1 -> xbuf0
    rgcn_aggregate_b<<<agrid, tb, 0, stream>>>(xbuf1, row_ptr, cnt, epack, agg);
    rgcn_transform_mfma<<<tgrid, tb, 0, stream>>>(agg, xbuf1, wt + 2 * 12288, b[1], nullptr, xbuf0, 0);
    // Layer 2: xbuf0 -> d_out (fp32, no activation)
    rgcn_aggregate_b<<<agrid, tb, 0, stream>>>(xbuf0, row_ptr, cnt, epack, agg);
    rgcn_transform_mfma<<<tgrid, tb, 0, stream>>>(agg, xbuf0, wt + 4 * 12288, b[2], outF, nullptr, 1);
}

// Round 6
// 382.215 us; speedup vs baseline: 1.8057x; 1.1844x over previous
//
#include <hip/hip_runtime.h>

#define NN 100000
#define NE 1000000
#define DIM 64
#define ZPITCH 200      // LDS row pitch in bf16 for transform tile
#define SCHUNK 1024
#define SBLOCKS ((NN + SCHUNK - 1) / SCHUNK)   // 98

typedef __attribute__((ext_vector_type(8))) short short8;
typedef __attribute__((ext_vector_type(4))) float f32x4;

__device__ __forceinline__ float bf2f(ushort u) {
    union { uint i; float f; } c; c.i = ((uint)u) << 16; return c.f;
}
__device__ __forceinline__ ushort f2bf(float f) {
    union { float f; uint i; } c; c.f = f;
    uint u = c.i;
    return (ushort)((u + 0x7FFFu + ((u >> 16) & 1u)) >> 16);   // RNE
}

// ---------------- CSR build (per-(dst,etype) counts) ----------------
__global__ __launch_bounds__(256) void zero_counts2(int* cnt2) {
    int i = blockIdx.x * 256 + threadIdx.x;
    if (i < 2 * NN) cnt2[i] = 0;
}

// Count per (dst, etype) AND record each edge's rank within its bucket.
__global__ __launch_bounds__(256) void count_rank2(const int* __restrict__ dst,
                                                   const int* __restrict__ et,
                                                   int* __restrict__ cnt2,
                                                   int* __restrict__ rank) {
    int e = blockIdx.x * 256 + threadIdx.x;
    if (e < NE) rank[e] = atomicAdd(&cnt2[dst[e] * 2 + et[e]], 1);
}

__global__ __launch_bounds__(256) void scan_partial2(const int* __restrict__ cnt2,
                                                     int* __restrict__ bsum) {
    int t = threadIdx.x, lane = t & 63, wid = t >> 6;
    int base = blockIdx.x * SCHUNK + t * 4;
    int s = 0;
#pragma unroll
    for (int k = 0; k < 4; ++k) {
        int i = base + k;
        if (i < NN) s += cnt2[2 * i] + cnt2[2 * i + 1];
    }
#pragma unroll
    for (int off = 32; off > 0; off >>= 1) s += __shfl_down(s, off, 64);
    __shared__ int wtot[4];
    if (lane == 0) wtot[wid] = s;
    __syncthreads();
    if (t == 0) bsum[blockIdx.x] = wtot[0] + wtot[1] + wtot[2] + wtot[3];
}

__global__ __launch_bounds__(128) void scan_bsums(const int* __restrict__ bsum,
                                                  int* __restrict__ bsum_ex) {
    __shared__ int sh[128];
    int t = threadIdx.x;
    int v = (t < SBLOCKS) ? bsum[t] : 0;
    sh[t] = v;
    __syncthreads();
    for (int off = 1; off < 128; off <<= 1) {
        int u = (t >= off) ? sh[t - off] : 0;
        __syncthreads();
        sh[t] += u;
        __syncthreads();
    }
    if (t < SBLOCKS) bsum_ex[t] = sh[t] - v;
}

__global__ __launch_bounds__(256) void scan_final2(const int* __restrict__ cnt2,
                                                   const int* __restrict__ bsum_ex,
                                                   int* __restrict__ row_ptr) {
    int t = threadIdx.x, lane = t & 63, wid = t >> 6;
    int base = blockIdx.x * SCHUNK + t * 4;
    int c[4];
#pragma unroll
    for (int k = 0; k < 4; ++k) {
        int i = base + k;
        c[k] = (i < NN) ? (cnt2[2 * i] + cnt2[2 * i + 1]) : 0;
    }
    int s = c[0] + c[1] + c[2] + c[3];
    int incl = s;
#pragma unroll
    for (int off = 1; off < 64; off <<= 1) {
        int u = __shfl_up(incl, off, 64);
        if (lane >= off) incl += u;
    }
    __shared__ int wtot[4];
    if (lane == 63) wtot[wid] = incl;
    __syncthreads();
    int woff = 0;
    for (int w = 0; w < wid; ++w) woff += wtot[w];
    int run = bsum_ex[blockIdx.x] + woff + (incl - s);
#pragma unroll
    for (int k = 0; k < 4; ++k) {
        int i = base + k;
        if (i < NN) row_ptr[i] = run;
        run += c[k];
    }
}

// Fill: relation-0 edges first within each dst row, then relation-1. No atomics.
__global__ __launch_bounds__(256) void fill_edges3(const int* __restrict__ src,
                                                   const int* __restrict__ dst,
                                                   const int* __restrict__ et,
                                                   const int* __restrict__ rank,
                                                   const int* __restrict__ row_ptr,
                                                   const int* __restrict__ cnt2,
                                                   int* __restrict__ esrc) {
    int e = blockIdx.x * 256 + threadIdx.x;
    if (e < NE) {
        int d = dst[e], r = et[e];
        int pos = row_ptr[d] + rank[e] + (r ? cnt2[2 * d] : 0);
        esrc[pos] = src[e];
    }
}

// ---------------- Feature convert (fp32 -> bf16 table) ----------------
__global__ __launch_bounds__(256) void convert_feat(const float* __restrict__ x,
                                                    ushort* __restrict__ xb) {
    int i = blockIdx.x * 256 + threadIdx.x;   // over NN*16 float4s (exact)
    float4 v = ((const float4*)x)[i];
    union { ushort u[4]; uint2 w; } o;
    o.u[0] = f2bf(v.x); o.u[1] = f2bf(v.y); o.u[2] = f2bf(v.z); o.u[3] = f2bf(v.w);
    *(uint2*)(xb + (size_t)i * 4) = o.w;
}

// ---------------- Weight prep: hi/lo bf16 split of [W0;W1;Ws] ----------------
__global__ __launch_bounds__(256) void prep_w(const float* __restrict__ W,
                                              const float* __restrict__ Ws,
                                              ushort* __restrict__ wt) {
    int idx = blockIdx.x * 256 + threadIdx.x;  // 0..12287 (grid 48)
    int k = idx >> 6, n = idx & 63;
    float v = (k < 128) ? W[k * 64 + n] : Ws[(k - 128) * 64 + n];
    ushort h = f2bf(v);
    ushort l = f2bf(v - bf2f(h));
    wt[n * 192 + k] = h;
    wt[12288 + n * 192 + k] = l;
}

// ---------------- Aggregation v3: 2 edges/wave, 2 dims/lane ----------------
// xbu: bf16 table viewed as uint (2 dims per uint, 32 uints per node row).
// Lanes 0-31 process even-indexed edges, 32-63 odd-indexed (h = lane>>5).
// Relation split is a loop phase (edges pre-sorted by etype within dst row):
// no per-edge relation test. Halves combined via shfl_xor(32) at node end.
__global__ __launch_bounds__(256) void rgcn_aggregate_b3(
    const uint* __restrict__ xbu, const int* __restrict__ row_ptr,
    const int* __restrict__ cnt2, const int* __restrict__ esrc,
    uint* __restrict__ aggu)
{
    int t = threadIdx.x, lane = t & 63, wid = t >> 6;
    int n = blockIdx.x * 4 + wid;
    if (n >= NN) return;
    int sl = lane & 31, h = lane >> 5;
    int start = row_ptr[n];
    int c0 = cnt2[2 * n], c1 = cnt2[2 * n + 1];

    float res[2][2];
    int pstart = start;
#pragma unroll
    for (int ph = 0; ph < 2; ++ph) {
        int cntp = ph ? c1 : c0;
        float ax = 0.f, ay = 0.f;
        for (int base = 0; base < cntp; base += 64) {
            int rem = cntp - base; if (rem > 64) rem = 64;
            int ev = (lane < rem) ? esrc[pstart + base + lane] : 0;
            int j = 0;
#pragma unroll 4
            for (; j + 1 < rem; j += 2) {
                int p = __shfl(ev, j + h, 64);        // half-wave edge select
                uint v = xbu[(size_t)p * 32 + sl];    // 2x128B per instruction
                union { uint u; float f; } lo, hi;
                lo.u = v << 16; hi.u = v & 0xFFFF0000u;
                ax += lo.f; ay += hi.f;
            }
            if (j < rem) {                            // odd tail: half-wave only
                int p = __shfl(ev, j, 64);
                if (h == 0) {
                    uint v = xbu[(size_t)p * 32 + sl];
                    union { uint u; float f; } lo, hi;
                    lo.u = v << 16; hi.u = v & 0xFFFF0000u;
                    ax += lo.f; ay += hi.f;
                }
            }
        }
        ax += __shfl_xor(ax, 32, 64);                 // combine even/odd halves
        ay += __shfl_xor(ay, 32, 64);
        res[ph][0] = ax; res[ph][1] = ay;
        pstart += cntp;
    }
    // agg row = [rel0 dims 0..63 | rel1 dims 0..63] bf16 = 64 uints.
    // lane h*32+sl writes uint (dims 2sl, 2sl+1) of block h.
    float ox = res[h][0], oy = res[h][1];
    uint val = ((uint)f2bf(oy) << 16) | (uint)f2bf(ox);
    aggu[(size_t)n * 64 + lane] = val;
}

// ---------------- MFMA transform (unchanged from R5) ----------------
__global__ __launch_bounds__(256) void rgcn_transform_mfma(
    const ushort* __restrict__ agg,   // [NN][128] bf16
    const ushort* __restrict__ xb,    // [NN][64]  bf16
    const ushort* __restrict__ wt,    // [2][64][192] bf16 (hi, lo)
    const float* __restrict__ bias,
    float* __restrict__ outf,
    ushort* __restrict__ xbn,
    int mode)
{
    __shared__ ushort sZ[64 * ZPITCH];   // 25.6 KB

    int t = threadIdx.x, lane = t & 63, wid = t >> 6;
    int quad = lane >> 4, l16 = lane & 15;

    short8 bh[6], bl[6];
    {
        const ushort* wh = wt + (size_t)(wid * 16 + l16) * 192;
        const ushort* wl = wh + 64 * 192;
#pragma unroll
        for (int kk = 0; kk < 6; ++kk) {
            bh[kk] = *(const short8*)(wh + kk * 32 + quad * 8);
            bl[kk] = *(const short8*)(wl + kk * 32 + quad * 8);
        }
    }
    float bv = bias[wid * 16 + l16];

    int n0 = blockIdx.x * 64;
    for (int i = t; i < 1024; i += 256) {           // agg: 64 rows x 16 uint4
        int node = i >> 4, c8 = i & 15;
        int n = n0 + node;
        uint4 v = {0u, 0u, 0u, 0u};
        if (n < NN) v = *(const uint4*)(agg + (size_t)n * 128 + c8 * 8);
        *(uint4*)(sZ + node * ZPITCH + c8 * 8) = v;
    }
    for (int i = t; i < 512; i += 256) {            // xb: 64 rows x 8 uint4
        int node = i >> 3, c8 = i & 7;
        int n = n0 + node;
        uint4 v = {0u, 0u, 0u, 0u};
        if (n < NN) v = *(const uint4*)(xb + (size_t)n * DIM + c8 * 8);
        *(uint4*)(sZ + node * ZPITCH + 128 + c8 * 8) = v;
    }
    __syncthreads();

    f32x4 acc[4];
#pragma unroll
    for (int mt = 0; mt < 4; ++mt) acc[mt] = (f32x4){bv, bv, bv, bv};

#pragma unroll
    for (int kk = 0; kk < 6; ++kk) {
#pragma unroll
        for (int mt = 0; mt < 4; ++mt) {
            short8 a = *(const short8*)(sZ + (mt * 16 + l16) * ZPITCH + kk * 32 + quad * 8);
            acc[mt] = __builtin_amdgcn_mfma_f32_16x16x32_bf16(a, bh[kk], acc[mt], 0, 0, 0);
            acc[mt] = __builtin_amdgcn_mfma_f32_16x16x32_bf16(a, bl[kk], acc[mt], 0, 0, 0);
        }
    }

    int col = wid * 16 + l16;
#pragma unroll
    for (int mt = 0; mt < 4; ++mt) {
#pragma unroll
        for (int r = 0; r < 4; ++r) {
            int node = n0 + mt * 16 + quad * 4 + r;
            if (node < NN) {
                float v = acc[mt][r];
                if (mode) outf[(size_t)node * DIM + col] = v;
                else      xbn[(size_t)node * DIM + col] = f2bf(fmaxf(v, 0.f));
            }
        }
    }
}

extern "C" void kernel_launch(void* const* d_in, const int* in_sizes, int n_in,
                              void* d_out, int out_size, void* d_ws, size_t ws_size,
                              hipStream_t stream)
{
    const float* feat = (const float*)d_in[0];
    const int*   src  = (const int*)d_in[1];
    const int*   dst  = (const int*)d_in[2];
    const int*   et   = (const int*)d_in[3];
    const float* W[3]  = { (const float*)d_in[4], (const float*)d_in[7], (const float*)d_in[10] };
    const float* Ws[3] = { (const float*)d_in[5], (const float*)d_in[8], (const float*)d_in[11] };
    const float* b[3]  = { (const float*)d_in[6], (const float*)d_in[9], (const float*)d_in[12] };

    // Workspace (~61 MB):
    //   agg   uint[NN*64]    25.6 MB
    //   xbuf0 ushort[NN*64]  12.8 MB
    //   xbuf1 ushort[NN*64]  12.8 MB
    //   wt    ushort[3][2*12288]
    //   esrc/rank int[NE]; cnt2 int[2*NN]; row_ptr int[NN]; bsum/bsum_ex
    uint*   agg   = (uint*)d_ws;
    ushort* xbuf0 = (ushort*)(agg + (size_t)NN * 64);
    ushort* xbuf1 = xbuf0 + (size_t)NN * 64;
    ushort* wt    = xbuf1 + (size_t)NN * 64;
    int* esrc    = (int*)(wt + 3 * 2 * 12288);
    int* rank    = esrc + NE;
    int* cnt2    = rank + NE;
    int* row_ptr = cnt2 + 2 * NN;
    int* bsum    = row_ptr + NN;
    int* bsum_ex = bsum + SBLOCKS;
    float* outF  = (float*)d_out;

    const dim3 tb(256);
    const int zgrid = (2 * NN + 255) / 256;  // 782
    const int egrid = (NE + 255) / 256;      // 3907
    const int tgrid = (NN + 63) / 64;        // 1563
    const int agrid = NN / 4;                // 25000

    // CSR build (relation-sorted rows)
    zero_counts2<<<zgrid, tb, 0, stream>>>(cnt2);
    count_rank2<<<egrid, tb, 0, stream>>>(dst, et, cnt2, rank);
    scan_partial2<<<SBLOCKS, tb, 0, stream>>>(cnt2, bsum);
    scan_bsums<<<1, 128, 0, stream>>>(bsum, bsum_ex);
    scan_final2<<<SBLOCKS, tb, 0, stream>>>(cnt2, bsum_ex, row_ptr);
    fill_edges3<<<egrid, tb, 0, stream>>>(src, dst, et, rank, row_ptr, cnt2, esrc);

    prep_w<<<48, tb, 0, stream>>>(W[0], Ws[0], wt);
    prep_w<<<48, tb, 0, stream>>>(W[1], Ws[1], wt + 2 * 12288);
    prep_w<<<48, tb, 0, stream>>>(W[2], Ws[2], wt + 4 * 12288);
    convert_feat<<<NN * 16 / 256, tb, 0, stream>>>(feat, xbuf0);

    // Layer 0: xbuf0 -> xbuf1 = bf16(relu(out0))
    rgcn_aggregate_b3<<<agrid, tb, 0, stream>>>((const uint*)xbuf0, row_ptr, cnt2, esrc, agg);
    rgcn_transform_mfma<<<tgrid, tb, 0, stream>>>((const ushort*)agg, xbuf0, wt, b[0], nullptr, xbuf1, 0);
    // Layer 1: xbuf1 -> xbuf0
    rgcn_aggregate_b3<<<agrid, tb, 0, stream>>>((const uint*)xbuf1, row_ptr, cnt2, esrc, agg);
    rgcn_transform_mfma<<<tgrid, tb, 0, stream>>>((const ushort*)agg, xbuf1, wt + 2 * 12288, b[1], nullptr, xbuf0, 0);
    // Layer 2: xbuf0 -> d_out (fp32, no activation)
    rgcn_aggregate_b3<<<agrid, tb, 0, stream>>>((const uint*)xbuf0, row_ptr, cnt2, esrc, agg);
    rgcn_transform_mfma<<<tgrid, tb, 0, stream>>>((const ushort*)agg, xbuf0, wt + 4 * 12288, b[2], outF, nullptr, 1);
}

// Round 7
// 380.945 us; speedup vs baseline: 1.8118x; 1.0033x over previous
//
#include <hip/hip_runtime.h>

#define NN 100000
#define NE 1000000
#define DIM 64
#define ZPITCH 200      // LDS row pitch in bf16 for transform tile
#define SCHUNK 1024
#define SBLOCKS ((NN + SCHUNK - 1) / SCHUNK)   // 98

typedef __attribute__((ext_vector_type(8))) short short8;
typedef __attribute__((ext_vector_type(4))) float f32x4;

__device__ __forceinline__ float bf2f(ushort u) {
    union { uint i; float f; } c; c.i = ((uint)u) << 16; return c.f;
}
__device__ __forceinline__ ushort f2bf(float f) {
    union { float f; uint i; } c; c.f = f;
    uint u = c.i;
    return (ushort)((u + 0x7FFFu + ((u >> 16) & 1u)) >> 16);   // RNE
}

// ---------------- CSR build (per-(dst,etype) counts) ----------------
__global__ __launch_bounds__(256) void zero_counts2(int* cnt2) {
    int i = blockIdx.x * 256 + threadIdx.x;
    if (i < 2 * NN) cnt2[i] = 0;
}

// Count per (dst, etype) AND record each edge's rank within its bucket.
__global__ __launch_bounds__(256) void count_rank2(const int* __restrict__ dst,
                                                   const int* __restrict__ et,
                                                   int* __restrict__ cnt2,
                                                   int* __restrict__ rank) {
    int e = blockIdx.x * 256 + threadIdx.x;
    if (e < NE) rank[e] = atomicAdd(&cnt2[dst[e] * 2 + et[e]], 1);
}

__global__ __launch_bounds__(256) void scan_partial2(const int* __restrict__ cnt2,
                                                     int* __restrict__ bsum) {
    int t = threadIdx.x, lane = t & 63, wid = t >> 6;
    int base = blockIdx.x * SCHUNK + t * 4;
    int s = 0;
#pragma unroll
    for (int k = 0; k < 4; ++k) {
        int i = base + k;
        if (i < NN) s += cnt2[2 * i] + cnt2[2 * i + 1];
    }
#pragma unroll
    for (int off = 32; off > 0; off >>= 1) s += __shfl_down(s, off, 64);
    __shared__ int wtot[4];
    if (lane == 0) wtot[wid] = s;
    __syncthreads();
    if (t == 0) bsum[blockIdx.x] = wtot[0] + wtot[1] + wtot[2] + wtot[3];
}

__global__ __launch_bounds__(128) void scan_bsums(const int* __restrict__ bsum,
                                                  int* __restrict__ bsum_ex) {
    __shared__ int sh[128];
    int t = threadIdx.x;
    int v = (t < SBLOCKS) ? bsum[t] : 0;
    sh[t] = v;
    __syncthreads();
    for (int off = 1; off < 128; off <<= 1) {
        int u = (t >= off) ? sh[t - off] : 0;
        __syncthreads();
        sh[t] += u;
        __syncthreads();
    }
    if (t < SBLOCKS) bsum_ex[t] = sh[t] - v;
}

__global__ __launch_bounds__(256) void scan_final2(const int* __restrict__ cnt2,
                                                   const int* __restrict__ bsum_ex,
                                                   int* __restrict__ row_ptr) {
    int t = threadIdx.x, lane = t & 63, wid = t >> 6;
    int base = blockIdx.x * SCHUNK + t * 4;
    int c[4];
#pragma unroll
    for (int k = 0; k < 4; ++k) {
        int i = base + k;
        c[k] = (i < NN) ? (cnt2[2 * i] + cnt2[2 * i + 1]) : 0;
    }
    int s = c[0] + c[1] + c[2] + c[3];
    int incl = s;
#pragma unroll
    for (int off = 1; off < 64; off <<= 1) {
        int u = __shfl_up(incl, off, 64);
        if (lane >= off) incl += u;
    }
    __shared__ int wtot[4];
    if (lane == 63) wtot[wid] = incl;
    __syncthreads();
    int woff = 0;
    for (int w = 0; w < wid; ++w) woff += wtot[w];
    int run = bsum_ex[blockIdx.x] + woff + (incl - s);
#pragma unroll
    for (int k = 0; k < 4; ++k) {
        int i = base + k;
        if (i < NN) row_ptr[i] = run;
        run += c[k];
    }
}

// Fill: relation-0 edges first within each dst row, then relation-1. No atomics.
__global__ __launch_bounds__(256) void fill_edges3(const int* __restrict__ src,
                                                   const int* __restrict__ dst,
                                                   const int* __restrict__ et,
                                                   const int* __restrict__ rank,
                                                   const int* __restrict__ row_ptr,
                                                   const int* __restrict__ cnt2,
                                                   int* __restrict__ esrc) {
    int e = blockIdx.x * 256 + threadIdx.x;
    if (e < NE) {
        int d = dst[e], r = et[e];
        int pos = row_ptr[d] + rank[e] + (r ? cnt2[2 * d] : 0);
        esrc[pos] = src[e];
    }
}

// ---------------- Feature convert (fp32 -> bf16 table) ----------------
__global__ __launch_bounds__(256) void convert_feat(const float* __restrict__ x,
                                                    ushort* __restrict__ xb) {
    int i = blockIdx.x * 256 + threadIdx.x;   // over NN*16 float4s (exact)
    float4 v = ((const float4*)x)[i];
    union { ushort u[4]; uint2 w; } o;
    o.u[0] = f2bf(v.x); o.u[1] = f2bf(v.y); o.u[2] = f2bf(v.z); o.u[3] = f2bf(v.w);
    *(uint2*)(xb + (size_t)i * 4) = o.w;
}

// ---------------- Weight prep: hi/lo bf16 split of [W0;W1;Ws] ----------------
__global__ __launch_bounds__(256) void prep_w(const float* __restrict__ W,
                                              const float* __restrict__ Ws,
                                              ushort* __restrict__ wt) {
    int idx = blockIdx.x * 256 + threadIdx.x;  // 0..12287 (grid 48)
    int k = idx >> 6, n = idx & 63;
    float v = (k < 128) ? W[k * 64 + n] : Ws[(k - 128) * 64 + n];
    ushort h = f2bf(v);
    ushort l = f2bf(v - bf2f(h));
    wt[n * 192 + k] = h;
    wt[12288 + n * 192 + k] = l;
}

// ---------------- Aggregation v4: readlane broadcast, no ds_bpermute --------
// xbu: bf16 table viewed as uint (2 dims per uint, 32 uints per node row).
// One wave per node. 2 edges per iteration: half-wave h processes edge j+h
// (32 lanes x uint = 128 B row each). Edge indices broadcast with
// v_readlane (uniform j) -> pure VALU, no LDS-pipe bpermute in the hot loop.
// Single esrc preload per 64-edge chunk covers BOTH relation phases; the
// relation split is the local boundary e0 = c0 - base (rows are rel-sorted).
#define UNPACK_ADD(v, ax, ay) { union {uint u; float f;} lo_, hi_;            \
    lo_.u = (v) << 16; hi_.u = (v) & 0xFFFF0000u; (ax) += lo_.f; (ay) += hi_.f; }

__global__ __launch_bounds__(256) void rgcn_aggregate_b4(
    const uint* __restrict__ xbu, const int* __restrict__ row_ptr,
    const int* __restrict__ cnt2, const int* __restrict__ esrc,
    uint* __restrict__ aggu)
{
    int t = threadIdx.x, lane = t & 63, wid = t >> 6;
    int n = blockIdx.x * 4 + wid;
    if (n >= NN) return;
    int sl = lane & 31, h = lane >> 5;
    int start = row_ptr[n];
    int c0 = cnt2[2 * n], c1 = cnt2[2 * n + 1];
    int deg = c0 + c1;

    const uint* xrow = xbu + sl;     // lane-fixed column offset
    float a00 = 0.f, a01 = 0.f, a10 = 0.f, a11 = 0.f;   // acc[rel][x/y]

    for (int base = 0; base < deg; base += 64) {
        int rem = deg - base; if (rem > 64) rem = 64;
        int ev = (lane < rem) ? esrc[start + base + lane] : 0;
        int e0 = c0 - base;
        if (e0 < 0) e0 = 0; if (e0 > rem) e0 = rem;

        int j = 0;
#pragma unroll 2
        for (; j + 1 < e0; j += 2) {               // relation 0 pairs
            int p0 = __builtin_amdgcn_readlane(ev, j);
            int p1 = __builtin_amdgcn_readlane(ev, j + 1);
            uint v = xrow[(size_t)(h ? p1 : p0) * 32];
            UNPACK_ADD(v, a00, a01);
        }
        if (j < e0) {                              // odd tail: half 0 only
            int p = __builtin_amdgcn_readlane(ev, j);
            if (!h) {
                uint v = xrow[(size_t)p * 32];
                UNPACK_ADD(v, a00, a01);
            }
        }
        j = e0;
#pragma unroll 2
        for (; j + 1 < rem; j += 2) {              // relation 1 pairs
            int p0 = __builtin_amdgcn_readlane(ev, j);
            int p1 = __builtin_amdgcn_readlane(ev, j + 1);
            uint v = xrow[(size_t)(h ? p1 : p0) * 32];
            UNPACK_ADD(v, a10, a11);
        }
        if (j < rem) {                             // odd tail: half 0 only
            int p = __builtin_amdgcn_readlane(ev, j);
            if (!h) {
                uint v = xrow[(size_t)p * 32];
                UNPACK_ADD(v, a10, a11);
            }
        }
    }

    a00 += __shfl_xor(a00, 32, 64);                // combine half-waves
    a01 += __shfl_xor(a01, 32, 64);
    a10 += __shfl_xor(a10, 32, 64);
    a11 += __shfl_xor(a11, 32, 64);

    // agg row = [rel0 dims 0..63 | rel1 dims 0..63] bf16 = 64 uints.
    // lane h*32+sl writes dims (2sl, 2sl+1) of relation h.
    float ox = h ? a10 : a00, oy = h ? a11 : a01;
    aggu[(size_t)n * 64 + lane] = ((uint)f2bf(oy) << 16) | (uint)f2bf(ox);
}

// ---------------- MFMA transform (unchanged) ----------------
__global__ __launch_bounds__(256) void rgcn_transform_mfma(
    const ushort* __restrict__ agg,   // [NN][128] bf16
    const ushort* __restrict__ xb,    // [NN][64]  bf16
    const ushort* __restrict__ wt,    // [2][64][192] bf16 (hi, lo)
    const float* __restrict__ bias,
    float* __restrict__ outf,
    ushort* __restrict__ xbn,
    int mode)
{
    __shared__ ushort sZ[64 * ZPITCH];   // 25.6 KB

    int t = threadIdx.x, lane = t & 63, wid = t >> 6;
    int quad = lane >> 4, l16 = lane & 15;

    short8 bh[6], bl[6];
    {
        const ushort* wh = wt + (size_t)(wid * 16 + l16) * 192;
        const ushort* wl = wh + 64 * 192;
#pragma unroll
        for (int kk = 0; kk < 6; ++kk) {
            bh[kk] = *(const short8*)(wh + kk * 32 + quad * 8);
            bl[kk] = *(const short8*)(wl + kk * 32 + quad * 8);
        }
    }
    float bv = bias[wid * 16 + l16];

    int n0 = blockIdx.x * 64;
    for (int i = t; i < 1024; i += 256) {           // agg: 64 rows x 16 uint4
        int node = i >> 4, c8 = i & 15;
        int n = n0 + node;
        uint4 v = {0u, 0u, 0u, 0u};
        if (n < NN) v = *(const uint4*)(agg + (size_t)n * 128 + c8 * 8);
        *(uint4*)(sZ + node * ZPITCH + c8 * 8) = v;
    }
    for (int i = t; i < 512; i += 256) {            // xb: 64 rows x 8 uint4
        int node = i >> 3, c8 = i & 7;
        int n = n0 + node;
        uint4 v = {0u, 0u, 0u, 0u};
        if (n < NN) v = *(const uint4*)(xb + (size_t)n * DIM + c8 * 8);
        *(uint4*)(sZ + node * ZPITCH + 128 + c8 * 8) = v;
    }
    __syncthreads();

    f32x4 acc[4];
#pragma unroll
    for (int mt = 0; mt < 4; ++mt) acc[mt] = (f32x4){bv, bv, bv, bv};

#pragma unroll
    for (int kk = 0; kk < 6; ++kk) {
#pragma unroll
        for (int mt = 0; mt < 4; ++mt) {
            short8 a = *(const short8*)(sZ + (mt * 16 + l16) * ZPITCH + kk * 32 + quad * 8);
            acc[mt] = __builtin_amdgcn_mfma_f32_16x16x32_bf16(a, bh[kk], acc[mt], 0, 0, 0);
            acc[mt] = __builtin_amdgcn_mfma_f32_16x16x32_bf16(a, bl[kk], acc[mt], 0, 0, 0);
        }
    }

    int col = wid * 16 + l16;
#pragma unroll
    for (int mt = 0; mt < 4; ++mt) {
#pragma unroll
        for (int r = 0; r < 4; ++r) {
            int node = n0 + mt * 16 + quad * 4 + r;
            if (node < NN) {
                float v = acc[mt][r];
                if (mode) outf[(size_t)node * DIM + col] = v;
                else      xbn[(size_t)node * DIM + col] = f2bf(fmaxf(v, 0.f));
            }
        }
    }
}

extern "C" void kernel_launch(void* const* d_in, const int* in_sizes, int n_in,
                              void* d_out, int out_size, void* d_ws, size_t ws_size,
                              hipStream_t stream)
{
    const float* feat = (const float*)d_in[0];
    const int*   src  = (const int*)d_in[1];
    const int*   dst  = (const int*)d_in[2];
    const int*   et   = (const int*)d_in[3];
    const float* W[3]  = { (const float*)d_in[4], (const float*)d_in[7], (const float*)d_in[10] };
    const float* Ws[3] = { (const float*)d_in[5], (const float*)d_in[8], (const float*)d_in[11] };
    const float* b[3]  = { (const float*)d_in[6], (const float*)d_in[9], (const float*)d_in[12] };

    // Workspace (~61 MB):
    //   agg   uint[NN*64]    25.6 MB
    //   xbuf0 ushort[NN*64]  12.8 MB
    //   xbuf1 ushort[NN*64]  12.8 MB
    //   wt    ushort[3][2*12288]
    //   esrc/rank int[NE]; cnt2 int[2*NN]; row_ptr int[NN]; bsum/bsum_ex
    uint*   agg   = (uint*)d_ws;
    ushort* xbuf0 = (ushort*)(agg + (size_t)NN * 64);
    ushort* xbuf1 = xbuf0 + (size_t)NN * 64;
    ushort* wt    = xbuf1 + (size_t)NN * 64;
    int* esrc    = (int*)(wt + 3 * 2 * 12288);
    int* rank    = esrc + NE;
    int* cnt2    = rank + NE;
    int* row_ptr = cnt2 + 2 * NN;
    int* bsum    = row_ptr + NN;
    int* bsum_ex = bsum + SBLOCKS;
    float* outF  = (float*)d_out;

    const dim3 tb(256);
    const int zgrid = (2 * NN + 255) / 256;  // 782
    const int egrid = (NE + 255) / 256;      // 3907
    const int tgrid = (NN + 63) / 64;        // 1563
    const int agrid = NN / 4;                // 25000

    // CSR build (relation-sorted rows)
    zero_counts2<<<zgrid, tb, 0, stream>>>(cnt2);
    count_rank2<<<egrid, tb, 0, stream>>>(dst, et, cnt2, rank);
    scan_partial2<<<SBLOCKS, tb, 0, stream>>>(cnt2, bsum);
    scan_bsums<<<1, 128, 0, stream>>>(bsum, bsum_ex);
    scan_final2<<<SBLOCKS, tb, 0, stream>>>(cnt2, bsum_ex, row_ptr);
    fill_edges3<<<egrid, tb, 0, stream>>>(src, dst, et, rank, row_ptr, cnt2, esrc);

    prep_w<<<48, tb, 0, stream>>>(W[0], Ws[0], wt);
    prep_w<<<48, tb, 0, stream>>>(W[1], Ws[1], wt + 2 * 12288);
    prep_w<<<48, tb, 0, stream>>>(W[2], Ws[2], wt + 4 * 12288);
    convert_feat<<<NN * 16 / 256, tb, 0, stream>>>(feat, xbuf0);

    // Layer 0: xbuf0 -> xbuf1 = bf16(relu(out0))
    rgcn_aggregate_b4<<<agrid, tb, 0, stream>>>((const uint*)xbuf0, row_ptr, cnt2, esrc, agg);
    rgcn_transform_mfma<<<tgrid, tb, 0, stream>>>((const ushort*)agg, xbuf0, wt, b[0], nullptr, xbuf1, 0);
    // Layer 1: xbuf1 -> xbuf0
    rgcn_aggregate_b4<<<agrid, tb, 0, stream>>>((const uint*)xbuf1, row_ptr, cnt2, esrc, agg);
    rgcn_transform_mfma<<<tgrid, tb, 0, stream>>>((const ushort*)agg, xbuf1, wt + 2 * 12288, b[1], nullptr, xbuf0, 0);
    // Layer 2: xbuf0 -> d_out (fp32, no activation)
    rgcn_aggregate_b4<<<agrid, tb, 0, stream>>>((const uint*)xbuf0, row_ptr, cnt2, esrc, agg);
    rgcn_transform_mfma<<<tgrid, tb, 0, stream>>>((const ushort*)agg, xbuf0, wt + 4 * 12288, b[2], outF, nullptr, 1);
}